// Round 9
// baseline (303.285 us; speedup 1.0000x reference)
//
#include <hip/hip_runtime.h>
#include <math.h>

#define TW 3072
#define TH 3072
#define NPIX (TW*TH)

__device__ __forceinline__ int qcode(float r, float g, float b) {
    int ir = min(max((int)rintf(__fmul_rn(r, 31.f)), 0), 31);
    int ig = min(max((int)rintf(__fmul_rn(g, 31.f)), 0), 31);
    int ib = min(max((int)rintf(__fmul_rn(b, 31.f)), 0), 31);
    return ir * 1024 + ig * 32 + ib;
}

__device__ __forceinline__ float grayf(float r, float g, float b) {
    // no FMA contraction: threshold-sensitive path must match numpy bit-closely
    return __fadd_rn(__fadd_rn(__fmul_rn(0.299f, r), __fmul_rn(0.587f, g)),
                     __fmul_rn(0.114f, b));
}

// ---------------- pass 1: init scalars + gray + code + per-block LDS histogram ----------------
// 256 blocks x 1024 threads; 36864 px/block -> u16-safe bins. DS-atomic pipe is
// the ~40us floor here (R3 split measurement); restructures don't move it.
// scal[0]=magmax bits, scal[1]=edmin bits, scal[2]=edmax bits,
// scal[3]=max hist count, scal[4]=min nonzero hist count.
__global__ __launch_bounds__(1024) void k_pre(const float4* __restrict__ img4,
                                              float4* __restrict__ gray4,
                                              ushort4* __restrict__ code4,
                                              unsigned* __restrict__ parthist,
                                              unsigned* __restrict__ scal) {
    if (blockIdx.x == 0 && threadIdx.x == 0) {
        scal[0] = 0u;
        scal[1] = 0x7F800000u;  // +inf
        scal[2] = 0u;
        scal[3] = 0u;
        scal[4] = 0xFFFFFFFFu;
    }
    __shared__ unsigned lh[16384];  // 64 KB: bins 2b (lo16) / 2b+1 (hi16)
    for (int t = threadIdx.x; t < 16384; t += 1024) lh[t] = 0u;
    __syncthreads();
    const int total4 = NPIX / 4;          // 2359296 = 9 * 262144 exactly
    const int stride = 256 * 1024;        // 262144 threads; 9 groups/thread, all in-range
    int base = blockIdx.x * 1024 + threadIdx.x;
    float4 rn = img4[base], gn = img4[base + total4], bn = img4[base + 2 * total4];
#pragma unroll
    for (int k = 0; k < 9; k++) {
        int p = base + k * stride;
        float4 r = rn, g = gn, b = bn;
        if (k < 8) {   // prefetch next group before consuming this one
            int pn = p + stride;
            rn = img4[pn]; gn = img4[pn + total4]; bn = img4[pn + 2 * total4];
        }
        float4 gy;
        gy.x = grayf(r.x, g.x, b.x); gy.y = grayf(r.y, g.y, b.y);
        gy.z = grayf(r.z, g.z, b.z); gy.w = grayf(r.w, g.w, b.w);
        gray4[p] = gy;
        int c0 = qcode(r.x, g.x, b.x), c1 = qcode(r.y, g.y, b.y);
        int c2 = qcode(r.z, g.z, b.z), c3 = qcode(r.w, g.w, b.w);
        atomicAdd(&lh[c0 >> 1], (c0 & 1) ? 0x10000u : 1u);
        atomicAdd(&lh[c1 >> 1], (c1 & 1) ? 0x10000u : 1u);
        atomicAdd(&lh[c2 >> 1], (c2 & 1) ? 0x10000u : 1u);
        atomicAdd(&lh[c3 >> 1], (c3 & 1) ? 0x10000u : 1u);
        ushort4 cc;
        cc.x = (unsigned short)c0; cc.y = (unsigned short)c1;
        cc.z = (unsigned short)c2; cc.w = (unsigned short)c3;
        code4[p] = cc;
    }
    __syncthreads();
    unsigned* dst = parthist + (size_t)blockIdx.x * 16384;
    for (int t = threadIdx.x; t < 16384; t += 1024) dst[t] = lh[t];
}

// ---------------- pass 2: reduce 256 partials -> cstab + max/min-nonzero ----------------
__global__ __launch_bounds__(1024) void k_reduce(const unsigned* __restrict__ parthist,
                                                 float* __restrict__ cstab,
                                                 unsigned* __restrict__ scal) {
    __shared__ unsigned slo[1024], shi[1024];
    int tid = threadIdx.x;
    int tsub = tid >> 6;          // wave index 0..15
    int pl = tid & 63;            // lane
    int b = blockIdx.x * 64 + pl; // bin-pair handled by this lane-column
    unsigned lo = 0u, hi = 0u;
#pragma unroll
    for (int j = 0; j < 16; j++) {
        unsigned v = parthist[(size_t)(tsub * 16 + j) * 16384 + b];
        lo += v & 0xFFFFu;
        hi += v >> 16;
    }
    slo[tid] = lo;
    shi[tid] = hi;
    __syncthreads();
    if (tid < 64) {
        unsigned Lo = 0u, Hi = 0u;
#pragma unroll
        for (int t = 0; t < 16; t++) { Lo += slo[t * 64 + tid]; Hi += shi[t * 64 + tid]; }
        const float N = (float)NPIX;
        int bb = blockIdx.x * 64 + tid;
        // identical expression to the per-pixel original
        cstab[2 * bb]     = -logf((float)Lo / N + 1e-9f) * 1.5f;
        cstab[2 * bb + 1] = -logf((float)Hi / N + 1e-9f) * 1.5f;
        unsigned mx = max(Lo, Hi);
        unsigned mn = 0xFFFFFFFFu;
        if (Lo) mn = Lo;
        if (Hi) mn = min(mn, Hi);
#pragma unroll
        for (int o = 32; o > 0; o >>= 1) {
            mx = max(mx, (unsigned)__shfl_down((int)mx, o));
            mn = min(mn, (unsigned)__shfl_down((int)mn, o));
        }
        if (tid == 0) { atomicMax(&scal[3], mx); atomicMin(&scal[4], mn); }
    }
}

// generic block max/min -> global atomics
__device__ __forceinline__ void blockMaxMinAtomic(float vmax, float vmin,
                                                  unsigned* pmax, unsigned* pmin) {
#pragma unroll
    for (int o = 32; o > 0; o >>= 1) {
        vmax = fmaxf(vmax, __shfl_down(vmax, o));
        vmin = fminf(vmin, __shfl_down(vmin, o));
    }
    __shared__ float smax[8], smin[8];
    int lane = threadIdx.x & 63, wv = threadIdx.x >> 6;
    if (lane == 0) { smax[wv] = vmax; smin[wv] = vmin; }
    __syncthreads();
    if (threadIdx.x == 0) {
        int nw = blockDim.x >> 6;
        float a = smax[0], b = smin[0];
        for (int k = 1; k < nw; k++) { a = fmaxf(a, smax[k]); b = fminf(b, smin[k]); }
        if (pmax) atomicMax(pmax, __float_as_uint(a));
        if (pmin) atomicMin(pmin, __float_as_uint(b));
    }
}

// ---------------- pass 3: fused 5x5 box + sobel + mag + magmax ----------------
// OCCUPANCY EXPERIMENT: 256x16 tile, LDS 41.9 KB, __launch_bounds__(512,6)
// -> 3 blocks/CU (24 waves) vs 2. R6 batched staging kept (tmp[12]).
#define BS_W 256
#define BS_H 16
#define GTW 264
#define GTH 22
#define BLW 260
#define BLH 18
__global__ __launch_bounds__(512, 6) void k_boxsobel(const float* __restrict__ g,
                                                     float* __restrict__ mag,
                                                     unsigned* __restrict__ scal) {
    __shared__ float GT[GTH * GTW];  // 22*264 = 5808 f = 23.2 KB
    __shared__ float BL[BLH * BLW];  // 18*260 = 4680 f = 18.7 KB
    int tid = threadIdx.x;
    int x0 = blockIdx.x * BS_W;
    int y0 = blockIdx.y * BS_H;
    {   // GTH*GTW = 5808 = 11*512 + 176 -> 12 batched rounds
        float tmp[12];
#pragma unroll
        for (int u = 0; u < 12; u++) {
            int t = tid + u * 512;
            int ly = t / GTW, lx = t - ly * GTW;
            int y = y0 - 3 + ly, x = x0 - 3 + lx;
            bool in = (t < GTH * GTW) && ((unsigned)y < TH) && ((unsigned)x < TW);
            tmp[u] = in ? g[(size_t)y * TW + x] : 0.f;
        }
#pragma unroll
        for (int u = 0; u < 12; u++) {
            int t = tid + u * 512;
            if (t < GTH * GTW) GT[t] = tmp[u];
        }
    }
    __syncthreads();
    // blurred: exact 25-term row-major order; 0 outside image (reference
    // zero-pads BLURRED for sobel, not gray)
    for (int t = tid; t < BLH * 65; t += 512) {
        int by = t / 65, gx = t - by * 65;
        int c0 = gx * 4;
        float acc[4] = {0.f, 0.f, 0.f, 0.f};
#pragma unroll
        for (int a = 0; a < 5; a++) {
            const float* rp = &GT[(by + a) * GTW + c0];
            float4 A = *(const float4*)rp;
            float4 B = *(const float4*)(rp + 4);
            float v[8] = {A.x, A.y, A.z, A.w, B.x, B.y, B.z, B.w};
#pragma unroll
            for (int j = 0; j < 4; j++)
#pragma unroll
                for (int b = 0; b < 5; b++)
                    acc[j] = __fadd_rn(acc[j], __fmul_rn(v[j + b], 0.04f));
        }
        int yb = y0 - 1 + by;
        float4 o;
        float* ov = (float*)&o;
#pragma unroll
        for (int j = 0; j < 4; j++) {
            int xb = x0 - 1 + c0 + j;
            ov[j] = ((unsigned)yb < TH && (unsigned)xb < TW) ? acc[j] : 0.f;
        }
        *(float4*)&BL[by * BLW + c0] = o;
    }
    __syncthreads();
    float tmax = 0.f;
    for (int t = tid; t < BS_H * 64; t += 512) {
        int oy = t >> 6, gx = t & 63;
        int c0 = gx * 4;
        float v[3][6];
#pragma unroll
        for (int a = 0; a < 3; a++) {
            const float* rp = &BL[(oy + a) * BLW + c0];
            float4 P = *(const float4*)rp;
            float2 Q = *(const float2*)(rp + 4);
            v[a][0] = P.x; v[a][1] = P.y; v[a][2] = P.z; v[a][3] = P.w;
            v[a][4] = Q.x; v[a][5] = Q.y;
        }
        float4 mo;
        float* mv = (float*)&mo;
#pragma unroll
        for (int j = 0; j < 4; j++) {
            float gxv = 0.f;
            gxv = __fadd_rn(gxv, __fmul_rn(-1.f, v[0][j + 0]));
            gxv = __fadd_rn(gxv, v[0][j + 2]);
            gxv = __fadd_rn(gxv, __fmul_rn(-2.f, v[1][j + 0]));
            gxv = __fadd_rn(gxv, __fmul_rn(2.f, v[1][j + 2]));
            gxv = __fadd_rn(gxv, __fmul_rn(-1.f, v[2][j + 0]));
            gxv = __fadd_rn(gxv, v[2][j + 2]);
            float gyv = 0.f;
            gyv = __fadd_rn(gyv, __fmul_rn(-1.f, v[0][j + 0]));
            gyv = __fadd_rn(gyv, __fmul_rn(-2.f, v[0][j + 1]));
            gyv = __fadd_rn(gyv, __fmul_rn(-1.f, v[0][j + 2]));
            gyv = __fadd_rn(gyv, v[2][j + 0]);
            gyv = __fadd_rn(gyv, __fmul_rn(2.f, v[2][j + 1]));
            gyv = __fadd_rn(gyv, v[2][j + 2]);
            float m = sqrtf(__fadd_rn(__fmul_rn(gxv, gxv), __fmul_rn(gyv, gyv)));
            mv[j] = m;
            tmax = fmaxf(tmax, m);
        }
        *(float4*)&mag[(size_t)(y0 + oy) * TW + x0 + c0] = mo;
    }
    blockMaxMinAtomic(tmax, 0.f, &scal[0], nullptr);
}

// ---------------- pass 4: fused threshold + H-gauss + V-gauss + ed min/max ----------------
// OCCUPANCY EXPERIMENT: 256x32 tile, E_H 46, LDS 49 KB, (512,6) -> 3 blocks/CU.
// Stage batched 5-wide (R6); V-pass rolling 4-row wave strips (bit-exact order).
#define GS_W 256
#define GS_H 32
#define E_H 46
#define EWB 10
__global__ __launch_bounds__(512, 6) void k_gauss(const float* __restrict__ mag,
                                                  float* __restrict__ ed,
                                                  const unsigned* __restrict__ scal,
                                                  unsigned* __restrict__ scalw) {
    __shared__ float wt[15];
    __shared__ unsigned E8[E_H * EWB];   // 1.8 KB bit-packed edge map
    __shared__ float EH[E_H * GS_W];     // 47.1 KB
    if (threadIdx.x == 0) {
        float w[15];
        float s = 0.f;
        for (int t = 0; t < 15; t++) {
            int c = t - 7;
            w[t] = expf(-(float)(c * c) * 0.125f);
            s += w[t];
        }
        for (int t = 0; t < 15; t++) wt[t] = w[t] / s;
    }
    __syncthreads();
    float magmax = __uint_as_float(scal[0]);
    float hi = __fmul_rn(magmax, 0.2f);
    float lo = __fmul_rn(hi, 0.3f);
    int tid = threadIdx.x;
    int lane = tid & 63, wave = tid >> 6;  // 8 waves
    int x0 = blockIdx.x * GS_W;
    int y0 = blockIdx.y * GS_H;
    // stage thresholded edge map, 1 bit/px via ballot; 0 outside image / col>=270.
    // 46 rows x 5 chunks = 230 items; wave-batched 5 at a time.
    for (int item0 = wave * 5; item0 < E_H * 5; item0 += 40) {
        float mv5[5];
#pragma unroll
        for (int u = 0; u < 5; u++) {
            int item = item0 + u;          // item0 <= 225 -> item <= 229 < 230: valid
            int ly = item / 5, ch = item - ly * 5;
            int y = y0 - 7 + ly;
            int lx = ch * 64 + lane;
            int x = x0 - 7 + lx;
            mv5[u] = ((unsigned)y < TH && lx < 270 && (unsigned)x < TW)
                         ? mag[(size_t)y * TW + x] : 0.f;
        }
#pragma unroll
        for (int u = 0; u < 5; u++) {
            int item = item0 + u;
            int ly = item / 5, ch = item - ly * 5;
            unsigned long long mask = __ballot(mv5[u] > lo && mv5[u] < hi);
            if (lane < 2) E8[ly * EWB + ch * 2 + lane] = (unsigned)(mask >> (32 * lane));
        }
    }
    __syncthreads();
    // horizontal 15-tap: 46 rows x 64 groups of 4 cols; 2 b32 reads/group
    for (int t = tid; t < E_H * 64; t += 512) {
        int ly = t >> 6, gx = t & 63;
        int c0 = gx * 4;
        int w0 = c0 >> 5, sh = c0 & 31;
        unsigned lo32 = E8[ly * EWB + w0];
        unsigned hi32 = E8[ly * EWB + w0 + 1];
        unsigned long long win = (((unsigned long long)hi32 << 32) | lo32) >> sh;
        float e[18];
#pragma unroll
        for (int j = 0; j < 18; j++) e[j] = (float)((unsigned)(win >> j) & 1u);
        float4 o;
        float* ov = (float*)&o;
#pragma unroll
        for (int j = 0; j < 4; j++) {
            float acc = 0.f;
#pragma unroll
            for (int k = 0; k < 15; k++) acc = fmaf(e[j + k], wt[k], acc);
            ov[j] = acc;
        }
        *(float4*)&EH[ly * GS_W + c0] = o;
    }
    __syncthreads();
    // vertical 15-tap + min/max: wave = 4-row strip (8 waves x 4 = 32 rows),
    // rolling window over 18 EH rows, each read once; k ascends per s (bit-exact).
    float tmin = INFINITY, tmax = 0.f;
    {
        int c0 = lane * 4;
        int r0 = wave * 4;
        float acc[4][4];
#pragma unroll
        for (int s = 0; s < 4; s++) {
            acc[s][0] = 0.f; acc[s][1] = 0.f; acc[s][2] = 0.f; acc[s][3] = 0.f;
        }
#pragma unroll
        for (int j = 0; j < 18; j++) {   // EH rows r0+j
            float4 v = *(const float4*)&EH[(r0 + j) * GS_W + c0];
#pragma unroll
            for (int s = 0; s < 4; s++) {
                int k = j - s;
                if (k >= 0 && k < 15) {
                    acc[s][0] = fmaf(v.x, wt[k], acc[s][0]);
                    acc[s][1] = fmaf(v.y, wt[k], acc[s][1]);
                    acc[s][2] = fmaf(v.z, wt[k], acc[s][2]);
                    acc[s][3] = fmaf(v.w, wt[k], acc[s][3]);
                }
            }
        }
#pragma unroll
        for (int s = 0; s < 4; s++) {
            float4 o;
            o.x = acc[s][0]; o.y = acc[s][1]; o.z = acc[s][2]; o.w = acc[s][3];
            *(float4*)&ed[(size_t)(y0 + r0 + s) * TW + x0 + c0] = o;
            tmin = fminf(tmin, fminf(fminf(o.x, o.y), fminf(o.z, o.w)));
            tmax = fmaxf(tmax, fmaxf(fmaxf(o.x, o.y), fmaxf(o.z, o.w)));
        }
    }
    blockMaxMinAtomic(tmax, tmin, &scalw[2], &scalw[1]);
}

// ---------------- pass 5: normalize + color sparsity (LDS u16 table) + sigmoid ----------------
// Vectorized table build (8 independent float4 loads/thread, u32-packed LDS
// writes); 512 blocks, grid-stride streaming (R7 structure).
__global__ __launch_bounds__(1024) void k_final(float4* __restrict__ io4,
                                                const ushort4* __restrict__ code4,
                                                const float* __restrict__ cstab,
                                                const unsigned* __restrict__ scal,
                                                const float* __restrict__ alphap,
                                                const float* __restrict__ betap) {
    __shared__ unsigned short cnS[32768];  // 64 KB
    const float N = (float)NPIX;
    float csmin = -logf((float)scal[3] / N + 1e-9f) * 1.5f;
    float csmax = -logf((float)scal[4] / N + 1e-9f) * 1.5f;
    float csrange = csmax - csmin + 1e-9f;
    {
        float4 cv[8];
#pragma unroll
        for (int u = 0; u < 8; u++)
            cv[u] = ((const float4*)cstab)[threadIdx.x + u * 1024];
        unsigned* cnS32 = (unsigned*)cnS;
#pragma unroll
        for (int u = 0; u < 8; u++) {
            int t4 = threadIdx.x + u * 1024;
            float vv[4] = {cv[u].x, cv[u].y, cv[u].z, cv[u].w};
            unsigned q[4];
#pragma unroll
            for (int j = 0; j < 4; j++) {
                float cn = (vv[j] - csmin) / csrange;
                int qi = (int)rintf(cn * 65535.f);
                q[j] = (unsigned)min(max(qi, 0), 65535);
            }
            cnS32[2 * t4]     = q[0] | (q[1] << 16);
            cnS32[2 * t4 + 1] = q[2] | (q[3] << 16);
        }
    }
    float edmin = __uint_as_float(scal[1]);
    float edmax = __uint_as_float(scal[2]);
    float edrange = edmax - edmin + 1e-9f;
    float alpha = *alphap, beta = *betap;
    __syncthreads();
    const int total4 = NPIX / 4;
    int stride = gridDim.x * blockDim.x;
    for (int p = blockIdx.x * blockDim.x + threadIdx.x; p < total4; p += stride) {
        float4 edv4 = io4[p];
        ushort4 cc = code4[p];
        float edv[4] = {edv4.x, edv4.y, edv4.z, edv4.w};
        unsigned short cv[4] = {cc.x, cc.y, cc.z, cc.w};
        float ov[4];
#pragma unroll
        for (int t = 0; t < 4; t++) {
            float en = (edv[t] - edmin) / edrange;
            float cn = (float)cnS[cv[t]] * (1.f / 65535.f);
            float x = alpha * en + beta * cn;
            ov[t] = 1.f / (1.f + expf(-x));
        }
        float4 o;
        o.x = ov[0]; o.y = ov[1]; o.z = ov[2]; o.w = ov[3];
        io4[p] = o;
    }
}

extern "C" void kernel_launch(void* const* d_in, const int* in_sizes, int n_in,
                              void* d_out, int out_size, void* d_ws, size_t ws_size,
                              hipStream_t stream) {
    const float* img = (const float*)d_in[0];
    const float* alphap = (const float*)d_in[1];
    const float* betap = (const float*)d_in[2];
    float* out = (float*)d_out;

    char* ws = (char*)d_ws;
    unsigned* scal = (unsigned*)ws;                                  // 64 B
    float* cstab = (float*)(ws + 1024 + 131072);                     // 128 KiB
    float* G = (float*)(ws + 524288);                                // 37.75 MB (gray)
    float* M = (float*)(ws + 524288 + (size_t)NPIX * 4);             // 37.75 MB (parthist -> mag)
    unsigned short* code = (unsigned short*)(ws + 524288 + (size_t)NPIX * 8);  // 18.9 MB
    unsigned* parthist = (unsigned*)M;  // 16.8 MB alias; dead before k_boxsobel writes mag

    hipLaunchKernelGGL(k_pre, dim3(256), dim3(1024), 0, stream,
                       (const float4*)img, (float4*)G, (ushort4*)code, parthist, scal);
    hipLaunchKernelGGL(k_reduce, dim3(256), dim3(1024), 0, stream, parthist, cstab, scal);
    hipLaunchKernelGGL(k_boxsobel, dim3(TW / BS_W, TH / BS_H), dim3(512), 0, stream,
                       G, M, scal);
    hipLaunchKernelGGL(k_gauss, dim3(TW / GS_W, TH / GS_H), dim3(512), 0, stream,
                       M, out, scal, scal);
    hipLaunchKernelGGL(k_final, dim3(512), dim3(1024), 0, stream, (float4*)out,
                       (const ushort4*)code, cstab, scal, alphap, betap);
}

// Round 10
// 284.888 us; speedup vs baseline: 1.0646x; 1.0646x over previous
//
#include <hip/hip_runtime.h>
#include <math.h>

#define TW 3072
#define TH 3072
#define NPIX (TW*TH)

__device__ __forceinline__ int qcode(float r, float g, float b) {
    int ir = min(max((int)rintf(__fmul_rn(r, 31.f)), 0), 31);
    int ig = min(max((int)rintf(__fmul_rn(g, 31.f)), 0), 31);
    int ib = min(max((int)rintf(__fmul_rn(b, 31.f)), 0), 31);
    return ir * 1024 + ig * 32 + ib;
}

__device__ __forceinline__ float grayf(float r, float g, float b) {
    // no FMA contraction: threshold-sensitive path must match numpy bit-closely
    return __fadd_rn(__fadd_rn(__fmul_rn(0.299f, r), __fmul_rn(0.587f, g)),
                     __fmul_rn(0.114f, b));
}

// ---------------- pass 1: pure streaming gray + code (no LDS, no atomics) ----------------
// scal[0]=magmax bits, scal[1]=edmin bits, scal[2]=edmax bits,
// scal[3]=max hist count, scal[4]=min nonzero hist count.
__global__ __launch_bounds__(256) void k_gray(const float4* __restrict__ img4,
                                              float4* __restrict__ gray4,
                                              ushort4* __restrict__ code4,
                                              unsigned* __restrict__ scal) {
    if (blockIdx.x == 0 && threadIdx.x == 0) {
        scal[0] = 0u;
        scal[1] = 0x7F800000u;  // +inf
        scal[2] = 0u;
        scal[3] = 0u;
        scal[4] = 0xFFFFFFFFu;
    }
    const int total4 = NPIX / 4;          // 2359296
    const int gstride = 2304 * 256;       // 589824 threads; 4 groups/thread exact
    int t0 = blockIdx.x * 256 + threadIdx.x;
#pragma unroll
    for (int k = 0; k < 4; k += 2) {
        int p = t0 + k * gstride;
        int q = p + gstride;
        float4 r0 = img4[p], g0 = img4[p + total4], b0 = img4[p + 2 * total4];
        float4 r1 = img4[q], g1 = img4[q + total4], b1 = img4[q + 2 * total4];
        float4 gy0, gy1;
        gy0.x = grayf(r0.x, g0.x, b0.x); gy0.y = grayf(r0.y, g0.y, b0.y);
        gy0.z = grayf(r0.z, g0.z, b0.z); gy0.w = grayf(r0.w, g0.w, b0.w);
        gy1.x = grayf(r1.x, g1.x, b1.x); gy1.y = grayf(r1.y, g1.y, b1.y);
        gy1.z = grayf(r1.z, g1.z, b1.z); gy1.w = grayf(r1.w, g1.w, b1.w);
        gray4[p] = gy0;
        gray4[q] = gy1;
        int c0 = qcode(r0.x, g0.x, b0.x), c1 = qcode(r0.y, g0.y, b0.y);
        int c2 = qcode(r0.z, g0.z, b0.z), c3 = qcode(r0.w, g0.w, b0.w);
        int d0 = qcode(r1.x, g1.x, b1.x), d1 = qcode(r1.y, g1.y, b1.y);
        int d2 = qcode(r1.z, g1.z, b1.z), d3 = qcode(r1.w, g1.w, b1.w);
        ushort4 cc, dd;
        cc.x = (unsigned short)c0; cc.y = (unsigned short)c1;
        cc.z = (unsigned short)c2; cc.w = (unsigned short)c3;
        dd.x = (unsigned short)d0; dd.y = (unsigned short)d1;
        dd.z = (unsigned short)d2; dd.w = (unsigned short)d3;
        code4[p] = cc;
        code4[q] = dd;
    }
}

// generic block max/min -> global atomics
__device__ __forceinline__ void blockMaxMinAtomic(float vmax, float vmin,
                                                  unsigned* pmax, unsigned* pmin) {
#pragma unroll
    for (int o = 32; o > 0; o >>= 1) {
        vmax = fmaxf(vmax, __shfl_down(vmax, o));
        vmin = fminf(vmin, __shfl_down(vmin, o));
    }
    __shared__ float smax[8], smin[8];
    int lane = threadIdx.x & 63, wv = threadIdx.x >> 6;
    if (lane == 0) { smax[wv] = vmax; smin[wv] = vmin; }
    __syncthreads();
    if (threadIdx.x == 0) {
        int nw = blockDim.x >> 6;
        float a = smax[0], b = smin[0];
        for (int k = 1; k < nw; k++) { a = fmaxf(a, smax[k]); b = fminf(b, smin[k]); }
        if (pmax) atomicMax(pmax, __float_as_uint(a));
        if (pmin) atomicMin(pmin, __float_as_uint(b));
    }
}

// ---------------- pass 2: box+sobel conv tiles WITH INTERLEAVED histogram blocks ----
// 1792 blocks x 512 threads: bid%7==6 -> histogram block (256 of them, co-resident
// with conv from dispatch start: DS-atomic work overlaps conv's BW/latency work).
// LDS via dynamic smem (64 KB): conv uses 58.7 KB (GT+BL), hist uses 64 KB.
// R7 conv geometry: 256x24, batched tmp[16] staging, no VGPR cap.
#define BS_W 256
#define BS_H 24
#define GTW 264
#define GTH 30
#define BLW 260
#define BLH 26
#define NCONV1 ((TW/BS_W)*(TH/BS_H))   // 1536
__global__ __launch_bounds__(512) void k_convhist(const float* __restrict__ g,
                                                  float* __restrict__ mag,
                                                  unsigned* __restrict__ scal,
                                                  const uint4* __restrict__ codeq,
                                                  unsigned* __restrict__ parthist) {
    extern __shared__ char dsm[];
    int tid = threadIdx.x;
    int bid = blockIdx.x;

    if (bid % 7 == 6) {
        // ---- histogram path: 36864 px/block (u16-safe), 4608 uint4 chunks ----
        unsigned* lh = (unsigned*)dsm;  // 16384 words: bins 2b (lo16) / 2b+1 (hi16)
        int hbid = bid / 7;             // 0..255
        for (int t = tid; t < 16384; t += 512) lh[t] = 0u;
        __syncthreads();
        const int cbase = hbid * 4608;
        uint4 w[9];
#pragma unroll
        for (int r = 0; r < 9; r++) w[r] = codeq[cbase + r * 512 + tid];
#pragma unroll
        for (int r = 0; r < 9; r++) {
            unsigned v;
            v = w[r].x;
            { unsigned c = v & 0xFFFFu; atomicAdd(&lh[c >> 1], (c & 1) ? 0x10000u : 1u); }
            { unsigned c = v >> 16;     atomicAdd(&lh[c >> 1], (c & 1) ? 0x10000u : 1u); }
            v = w[r].y;
            { unsigned c = v & 0xFFFFu; atomicAdd(&lh[c >> 1], (c & 1) ? 0x10000u : 1u); }
            { unsigned c = v >> 16;     atomicAdd(&lh[c >> 1], (c & 1) ? 0x10000u : 1u); }
            v = w[r].z;
            { unsigned c = v & 0xFFFFu; atomicAdd(&lh[c >> 1], (c & 1) ? 0x10000u : 1u); }
            { unsigned c = v >> 16;     atomicAdd(&lh[c >> 1], (c & 1) ? 0x10000u : 1u); }
            v = w[r].w;
            { unsigned c = v & 0xFFFFu; atomicAdd(&lh[c >> 1], (c & 1) ? 0x10000u : 1u); }
            { unsigned c = v >> 16;     atomicAdd(&lh[c >> 1], (c & 1) ? 0x10000u : 1u); }
        }
        __syncthreads();
        unsigned* dst = parthist + (size_t)hbid * 16384;
        for (int t = tid; t < 16384; t += 512) dst[t] = lh[t];
        return;
    }

    // ---- conv path (R7 verbatim) ----
    int cidx = bid - bid / 7;           // 0..1535
    float* GT = (float*)dsm;            // 30*264 floats
    float* BL = GT + GTH * GTW;         // 26*260 floats
    int x0 = (cidx % (TW / BS_W)) * BS_W;
    int y0 = (cidx / (TW / BS_W)) * BS_H;
    {   // GTH*GTW = 7920 = 15*512 + 240
        float tmp[16];
#pragma unroll
        for (int u = 0; u < 16; u++) {
            int t = tid + u * 512;
            int ly = t / GTW, lx = t - ly * GTW;
            int y = y0 - 3 + ly, x = x0 - 3 + lx;
            bool in = (t < GTH * GTW) && ((unsigned)y < TH) && ((unsigned)x < TW);
            tmp[u] = in ? g[(size_t)y * TW + x] : 0.f;
        }
#pragma unroll
        for (int u = 0; u < 16; u++) {
            int t = tid + u * 512;
            if (t < GTH * GTW) GT[t] = tmp[u];
        }
    }
    __syncthreads();
    // blurred: exact 25-term row-major order; 0 outside image (reference
    // zero-pads BLURRED for sobel, not gray)
    for (int t = tid; t < BLH * 65; t += 512) {
        int by = t / 65, gx = t - by * 65;
        int c0 = gx * 4;
        float acc[4] = {0.f, 0.f, 0.f, 0.f};
#pragma unroll
        for (int a = 0; a < 5; a++) {
            const float* rp = &GT[(by + a) * GTW + c0];
            float4 A = *(const float4*)rp;
            float4 B = *(const float4*)(rp + 4);
            float v[8] = {A.x, A.y, A.z, A.w, B.x, B.y, B.z, B.w};
#pragma unroll
            for (int j = 0; j < 4; j++)
#pragma unroll
                for (int b = 0; b < 5; b++)
                    acc[j] = __fadd_rn(acc[j], __fmul_rn(v[j + b], 0.04f));
        }
        int yb = y0 - 1 + by;
        float4 o;
        float* ov = (float*)&o;
#pragma unroll
        for (int j = 0; j < 4; j++) {
            int xb = x0 - 1 + c0 + j;
            ov[j] = ((unsigned)yb < TH && (unsigned)xb < TW) ? acc[j] : 0.f;
        }
        *(float4*)&BL[by * BLW + c0] = o;
    }
    __syncthreads();
    float tmax = 0.f;
    for (int t = tid; t < BS_H * 64; t += 512) {
        int oy = t >> 6, gx = t & 63;
        int c0 = gx * 4;
        float v[3][6];
#pragma unroll
        for (int a = 0; a < 3; a++) {
            const float* rp = &BL[(oy + a) * BLW + c0];
            float4 P = *(const float4*)rp;
            float2 Q = *(const float2*)(rp + 4);
            v[a][0] = P.x; v[a][1] = P.y; v[a][2] = P.z; v[a][3] = P.w;
            v[a][4] = Q.x; v[a][5] = Q.y;
        }
        float4 mo;
        float* mv = (float*)&mo;
#pragma unroll
        for (int j = 0; j < 4; j++) {
            float gxv = 0.f;
            gxv = __fadd_rn(gxv, __fmul_rn(-1.f, v[0][j + 0]));
            gxv = __fadd_rn(gxv, v[0][j + 2]);
            gxv = __fadd_rn(gxv, __fmul_rn(-2.f, v[1][j + 0]));
            gxv = __fadd_rn(gxv, __fmul_rn(2.f, v[1][j + 2]));
            gxv = __fadd_rn(gxv, __fmul_rn(-1.f, v[2][j + 0]));
            gxv = __fadd_rn(gxv, v[2][j + 2]);
            float gyv = 0.f;
            gyv = __fadd_rn(gyv, __fmul_rn(-1.f, v[0][j + 0]));
            gyv = __fadd_rn(gyv, __fmul_rn(-2.f, v[0][j + 1]));
            gyv = __fadd_rn(gyv, __fmul_rn(-1.f, v[0][j + 2]));
            gyv = __fadd_rn(gyv, v[2][j + 0]);
            gyv = __fadd_rn(gyv, __fmul_rn(2.f, v[2][j + 1]));
            gyv = __fadd_rn(gyv, v[2][j + 2]);
            float m = sqrtf(__fadd_rn(__fmul_rn(gxv, gxv), __fmul_rn(gyv, gyv)));
            mv[j] = m;
            tmax = fmaxf(tmax, m);
        }
        *(float4*)&mag[(size_t)(y0 + oy) * TW + x0 + c0] = mo;
    }
    blockMaxMinAtomic(tmax, 0.f, &scal[0], nullptr);
}

// ---------------- pass 3: threshold + gauss WITH INTERLEAVED reduce blocks ----------------
// 1024 blocks x 512 threads: bid&3==3 -> reduce block (256), else gauss tile (768).
// R7 gauss geometry: 256x48, E_H 62, batch-5 stage, V-pass 6-row rolling strips.
#define GS_W 256
#define GS_H 48
#define E_H 62
#define EWB 10
__global__ __launch_bounds__(512) void k_gaussred(const float* __restrict__ mag,
                                                  float* __restrict__ ed,
                                                  unsigned* __restrict__ scal,
                                                  const unsigned* __restrict__ parthist,
                                                  float* __restrict__ cstab) {
    __shared__ float wt[15];
    __shared__ unsigned E8[E_H * EWB];   // 2.4 KB bit-packed edge map
    __shared__ float EH[E_H * GS_W];     // 63.5 KB
    __shared__ unsigned slo[512], shi[512];  // 4 KB (reduce path)
    int tid = threadIdx.x;
    int bid = blockIdx.x;

    if ((bid & 3) == 3) {
        // ---- reduce path: 256 blocks; 8 waves x 32 partials each ----
        int rbid = bid >> 2;
        int tsub = tid >> 6;          // wave 0..7
        int pl = tid & 63;
        int b = rbid * 64 + pl;       // bin-pair
        unsigned lo = 0u, hi = 0u;
#pragma unroll 8
        for (int j = 0; j < 32; j++) {
            unsigned v = parthist[(size_t)(tsub * 32 + j) * 16384 + b];
            lo += v & 0xFFFFu;
            hi += v >> 16;
        }
        slo[tid] = lo;
        shi[tid] = hi;
        __syncthreads();
        if (tid < 64) {
            unsigned Lo = 0u, Hi = 0u;
#pragma unroll
            for (int t = 0; t < 8; t++) { Lo += slo[t * 64 + tid]; Hi += shi[t * 64 + tid]; }
            const float N = (float)NPIX;
            int bb = rbid * 64 + tid;
            // identical expression to the per-pixel original
            cstab[2 * bb]     = -logf((float)Lo / N + 1e-9f) * 1.5f;
            cstab[2 * bb + 1] = -logf((float)Hi / N + 1e-9f) * 1.5f;
            unsigned mx = max(Lo, Hi);
            unsigned mn = 0xFFFFFFFFu;
            if (Lo) mn = Lo;
            if (Hi) mn = min(mn, Hi);
#pragma unroll
            for (int o = 32; o > 0; o >>= 1) {
                mx = max(mx, (unsigned)__shfl_down((int)mx, o));
                mn = min(mn, (unsigned)__shfl_down((int)mn, o));
            }
            if (tid == 0) { atomicMax(&scal[3], mx); atomicMin(&scal[4], mn); }
        }
        return;
    }

    // ---- gauss path (R7 verbatim) ----
    int cidx = bid - (bid >> 2);         // 0..767
    int x0 = (cidx % (TW / GS_W)) * GS_W;
    int y0 = (cidx / (TW / GS_W)) * GS_H;
    if (threadIdx.x == 0) {
        float w[15];
        float s = 0.f;
        for (int t = 0; t < 15; t++) {
            int c = t - 7;
            w[t] = expf(-(float)(c * c) * 0.125f);
            s += w[t];
        }
        for (int t = 0; t < 15; t++) wt[t] = w[t] / s;
    }
    __syncthreads();
    float magmax = __uint_as_float(scal[0]);
    float hi = __fmul_rn(magmax, 0.2f);
    float lo = __fmul_rn(hi, 0.3f);
    int lane = tid & 63, wave = tid >> 6;  // 8 waves
    // stage thresholded edge map, 1 bit/px via ballot; 0 outside image / col>=270.
    // 62 rows x 5 chunks = 310 items; wave-batched 5 at a time.
    for (int item0 = wave * 5; item0 < E_H * 5; item0 += 40) {
        float mv5[5];
#pragma unroll
        for (int u = 0; u < 5; u++) {
            int item = item0 + u;          // max 309 < 310: always valid
            int ly = item / 5, ch = item - ly * 5;
            int y = y0 - 7 + ly;
            int lx = ch * 64 + lane;
            int x = x0 - 7 + lx;
            mv5[u] = ((unsigned)y < TH && lx < 270 && (unsigned)x < TW)
                         ? mag[(size_t)y * TW + x] : 0.f;
        }
#pragma unroll
        for (int u = 0; u < 5; u++) {
            int item = item0 + u;
            int ly = item / 5, ch = item - ly * 5;
            unsigned long long mask = __ballot(mv5[u] > lo && mv5[u] < hi);
            if (lane < 2) E8[ly * EWB + ch * 2 + lane] = (unsigned)(mask >> (32 * lane));
        }
    }
    __syncthreads();
    // horizontal 15-tap: 62 rows x 64 groups of 4 cols; 2 b32 reads/group
    for (int t = tid; t < E_H * 64; t += 512) {
        int ly = t >> 6, gx = t & 63;
        int c0 = gx * 4;
        int w0 = c0 >> 5, sh = c0 & 31;
        unsigned lo32 = E8[ly * EWB + w0];
        unsigned hi32 = E8[ly * EWB + w0 + 1];
        unsigned long long win = (((unsigned long long)hi32 << 32) | lo32) >> sh;
        float e[18];
#pragma unroll
        for (int j = 0; j < 18; j++) e[j] = (float)((unsigned)(win >> j) & 1u);
        float4 o;
        float* ov = (float*)&o;
#pragma unroll
        for (int j = 0; j < 4; j++) {
            float acc = 0.f;
#pragma unroll
            for (int k = 0; k < 15; k++) acc = fmaf(e[j + k], wt[k], acc);
            ov[j] = acc;
        }
        *(float4*)&EH[ly * GS_W + c0] = o;
    }
    __syncthreads();
    // vertical 15-tap + min/max: wave = 6-row strip, rolling window (bit-exact order)
    float tmin = INFINITY, tmax = 0.f;
    {
        int c0 = lane * 4;
        int r0 = wave * 6;               // 8 waves x 6 rows = 48
        float acc[6][4];
#pragma unroll
        for (int s = 0; s < 6; s++) {
            acc[s][0] = 0.f; acc[s][1] = 0.f; acc[s][2] = 0.f; acc[s][3] = 0.f;
        }
#pragma unroll
        for (int j = 0; j < 20; j++) {   // EH rows r0+j, each read once
            float4 v = *(const float4*)&EH[(r0 + j) * GS_W + c0];
#pragma unroll
            for (int s = 0; s < 6; s++) {
                int k = j - s;
                if (k >= 0 && k < 15) {  // k ascends per s: same order as before
                    acc[s][0] = fmaf(v.x, wt[k], acc[s][0]);
                    acc[s][1] = fmaf(v.y, wt[k], acc[s][1]);
                    acc[s][2] = fmaf(v.z, wt[k], acc[s][2]);
                    acc[s][3] = fmaf(v.w, wt[k], acc[s][3]);
                }
            }
        }
#pragma unroll
        for (int s = 0; s < 6; s++) {
            float4 o;
            o.x = acc[s][0]; o.y = acc[s][1]; o.z = acc[s][2]; o.w = acc[s][3];
            *(float4*)&ed[(size_t)(y0 + r0 + s) * TW + x0 + c0] = o;
            tmin = fminf(tmin, fminf(fminf(o.x, o.y), fminf(o.z, o.w)));
            tmax = fmaxf(tmax, fmaxf(fmaxf(o.x, o.y), fmaxf(o.z, o.w)));
        }
    }
    blockMaxMinAtomic(tmax, tmin, &scal[2], &scal[1]);
}

// ---------------- pass 4: normalize + color sparsity (LDS u16 table) + sigmoid ----------------
// Vectorized table build (8 independent float4 loads/thread, u32-packed LDS
// writes); 512 blocks, grid-stride streaming.
__global__ __launch_bounds__(1024) void k_final(float4* __restrict__ io4,
                                                const ushort4* __restrict__ code4,
                                                const float* __restrict__ cstab,
                                                const unsigned* __restrict__ scal,
                                                const float* __restrict__ alphap,
                                                const float* __restrict__ betap) {
    __shared__ unsigned short cnS[32768];  // 64 KB
    const float N = (float)NPIX;
    float csmin = -logf((float)scal[3] / N + 1e-9f) * 1.5f;
    float csmax = -logf((float)scal[4] / N + 1e-9f) * 1.5f;
    float csrange = csmax - csmin + 1e-9f;
    {
        float4 cv[8];
#pragma unroll
        for (int u = 0; u < 8; u++)
            cv[u] = ((const float4*)cstab)[threadIdx.x + u * 1024];
        unsigned* cnS32 = (unsigned*)cnS;
#pragma unroll
        for (int u = 0; u < 8; u++) {
            int t4 = threadIdx.x + u * 1024;
            float vv[4] = {cv[u].x, cv[u].y, cv[u].z, cv[u].w};
            unsigned q[4];
#pragma unroll
            for (int j = 0; j < 4; j++) {
                float cn = (vv[j] - csmin) / csrange;
                int qi = (int)rintf(cn * 65535.f);
                q[j] = (unsigned)min(max(qi, 0), 65535);
            }
            cnS32[2 * t4]     = q[0] | (q[1] << 16);
            cnS32[2 * t4 + 1] = q[2] | (q[3] << 16);
        }
    }
    float edmin = __uint_as_float(scal[1]);
    float edmax = __uint_as_float(scal[2]);
    float edrange = edmax - edmin + 1e-9f;
    float alpha = *alphap, beta = *betap;
    __syncthreads();
    const int total4 = NPIX / 4;
    int stride = gridDim.x * blockDim.x;
    for (int p = blockIdx.x * blockDim.x + threadIdx.x; p < total4; p += stride) {
        float4 edv4 = io4[p];
        ushort4 cc = code4[p];
        float edv[4] = {edv4.x, edv4.y, edv4.z, edv4.w};
        unsigned short cv[4] = {cc.x, cc.y, cc.z, cc.w};
        float ov[4];
#pragma unroll
        for (int t = 0; t < 4; t++) {
            float en = (edv[t] - edmin) / edrange;
            float cn = (float)cnS[cv[t]] * (1.f / 65535.f);
            float x = alpha * en + beta * cn;
            ov[t] = 1.f / (1.f + expf(-x));
        }
        float4 o;
        o.x = ov[0]; o.y = ov[1]; o.z = ov[2]; o.w = ov[3];
        io4[p] = o;
    }
}

extern "C" void kernel_launch(void* const* d_in, const int* in_sizes, int n_in,
                              void* d_out, int out_size, void* d_ws, size_t ws_size,
                              hipStream_t stream) {
    const float* img = (const float*)d_in[0];
    const float* alphap = (const float*)d_in[1];
    const float* betap = (const float*)d_in[2];
    float* out = (float*)d_out;

    char* ws = (char*)d_ws;
    unsigned* scal = (unsigned*)ws;                                  // 64 B
    float* cstab = (float*)(ws + 1024 + 131072);                     // 128 KiB
    float* G = (float*)(ws + 524288);                                // 37.75 MB (gray)
    float* M = (float*)(ws + 524288 + (size_t)NPIX * 4);             // 37.75 MB (mag)
    unsigned short* code = (unsigned short*)(ws + 524288 + (size_t)NPIX * 8);  // 18.9 MB
    // parthist written concurrently with mag in k_convhist -> disjoint slot after code
    unsigned* parthist = (unsigned*)(ws + 524288 + (size_t)NPIX * 10);  // 16.8 MB

    hipLaunchKernelGGL(k_gray, dim3(2304), dim3(256), 0, stream,
                       (const float4*)img, (float4*)G, (ushort4*)code, scal);
    hipLaunchKernelGGL(k_convhist, dim3(7 * 256), dim3(512), 65536, stream,
                       G, M, scal, (const uint4*)code, parthist);
    hipLaunchKernelGGL(k_gaussred, dim3(1024), dim3(512), 0, stream,
                       M, out, scal, parthist, cstab);
    hipLaunchKernelGGL(k_final, dim3(512), dim3(1024), 0, stream, (float4*)out,
                       (const ushort4*)code, cstab, scal, alphap, betap);
}